// Round 3
// baseline (88.818 us; speedup 1.0000x reference)
//
#include <hip/hip_runtime.h>

// CostVolume3D: B=8 H=128 W=256 C=8, D=23. out flat index L over [B*D,H,W].
//   disp = wflow[L/23] - ((L>>15)%23 - 11)
//   A_c  = feat_l[(L*8+c)/23]
//   V_c@x= feat_r[((rowbase+x)*8+c)/23], bilinear taps x0=clamp(floor(wp-disp)), x1=min(x0+1,255)
//
// Block = 1024 consecutive L (1024-aligned):
//  * never crosses a row (256|1024) nor an n=L>>15 boundary (1024|32768)
//  * feat_l quotients: offsets [8,368] in a window based at baseR=base4-8
//  * feat_r quotients: x0i-wp in [-12,+11] -> q0 in [qL-5, qL+4], +2 for hi
//    element -> offsets [3,373] in same window      (R2 bug #1: underflow)
//  * wflow offsets reach 48 -> sWF[64]              (R2 bug #2: off-by-one)
//  -> stage 384+384+64 floats in LDS, 4 outputs/thread from LDS,
//     incremental +8/+1 div-23 carries, one float4 store per thread.

#define WW 256
#define NOUT (8 * 128 * 256 * 23)   // 6,029,312 = 5888 blocks * 1024
#define FEAT_MAXQ 2097151           // B*H*W*C - 1
#define WF_MAX    262143u           // B*H*W - 1

__global__ __launch_bounds__(256) void costvol_kernel(
    const float* __restrict__ feat_l,
    const float* __restrict__ feat_r,
    const float* __restrict__ wflow,
    float* __restrict__ out)
{
    __shared__ float sFL[384];
    __shared__ float sFR[384];
    __shared__ float sWF[64];

    const unsigned L0     = blockIdx.x << 10;            // 1024 outputs/block
    const unsigned base4  = ((L0 * 8u) / 23u) & ~3u;
    const int      baseR  = (int)base4 - 8;              // window base (4-aligned)
    const unsigned wbase4 = (L0 / 23u) & ~3u;
    const float shiftf = (float)(int)((L0 >> 15) % 23u) - 11.0f;

    // ---- stage windows (coalesced, index-clamped; clamped lanes are padding) ----
    for (int t = (int)threadIdx.x; t < 384; t += 256) {
        int g = baseR + t;
        g = g < 0 ? 0 : (g > FEAT_MAXQ ? FEAT_MAXQ : g);
        sFL[t] = feat_l[g];
        sFR[t] = feat_r[g];
    }
    if (threadIdx.x < 64u) {
        unsigned g = wbase4 + threadIdx.x;
        g = g > WF_MAX ? WF_MAX : g;
        sWF[threadIdx.x] = wflow[g];
    }
    __syncthreads();

    const unsigned Lt      = L0 + threadIdx.x * 4u;      // 4 consecutive outputs
    const unsigned wp0     = Lt & 255u;
    const unsigned rowbase = Lt - wp0;                   // constant across the 4

    // incremental div-by-23 state
    unsigned mq = Lt / 23u, mr = Lt - mq * 23u;          // wflow index
    unsigned numL = Lt * 8u;
    unsigned qL = numL / 23u, rL = numL - qL * 23u;      // feat_l index

    float res[4];
    #pragma unroll
    for (int i = 0; i < 4; ++i) {
        float wfv  = sWF[mq - wbase4];
        float disp = wfv - shiftf;
        float xq   = (float)(int)(wp0 + (unsigned)i) - disp;
        float x0f  = floorf(xq);
        float frac = xq - x0f;                           // NOT clipped (matches ref)
        int x0i = (int)x0f;
        x0i = min(max(x0i, 0), WW - 1);
        int x1i = min(x0i + 1, WW - 1);

        int fL = (int)qL - baseR;
        float aLo = sFL[fL];
        float aHi = sFL[fL + 1];
        int sA = 23 - (int)rL;                           // c<sA -> aLo

        unsigned num0 = (rowbase + (unsigned)x0i) * 8u;
        unsigned q0 = num0 / 23u;
        unsigned r0 = num0 - q0 * 23u;
        int f0 = (int)q0 - baseR;
        float b0 = sFR[f0], b1 = sFR[f0 + 1], b2 = sFR[f0 + 2];
        int s0 = 23 - (int)r0;

        // tap x1: num1 = num0 + 8 (or == num0 when clamped at W-1)
        unsigned r1 = r0 + 8u;
        unsigned carry = (r1 >= 23u) ? 1u : 0u;
        r1 -= carry * 23u;
        if (x1i == x0i) { carry = 0u; r1 = r0; }
        int s1 = 23 - (int)r1;
        float h0 = carry ? b1 : b0;                      // x1-tap lo
        float h1 = carry ? b2 : b1;                      // x1-tap hi

        float om  = 1.0f - frac;
        float acc = 0.0f;
        #pragma unroll
        for (int c = 0; c < 8; ++c) {
            float A  = (c < sA) ? aLo : aHi;
            float V0 = (c < s0) ? b0 : b1;
            float V1 = (c < s1) ? h0 : h1;
            acc += fabsf(A - (V0 * om + V1 * frac));
        }
        res[i] = acc;

        // advance incremental indices for next output
        if (++mr == 23u) { mr = 0u; ++mq; }
        rL += 8u; if (rL >= 23u) { rL -= 23u; ++qL; }
    }

    *reinterpret_cast<float4*>(out + Lt) = make_float4(res[0], res[1], res[2], res[3]);
}

extern "C" void kernel_launch(void* const* d_in, const int* in_sizes, int n_in,
                              void* d_out, int out_size, void* d_ws, size_t ws_size,
                              hipStream_t stream) {
    const float* feat_l = (const float*)d_in[0];
    const float* feat_r = (const float*)d_in[1];
    const float* wflow  = (const float*)d_in[2];
    float* out = (float*)d_out;

    const int blocks = NOUT / 1024;   // 5888, exact
    costvol_kernel<<<blocks, 256, 0, stream>>>(feat_l, feat_r, wflow, out);
}